// Round 1
// baseline (426.091 us; speedup 1.0000x reference)
//
#include <hip/hip_runtime.h>
#include <math.h>

// SimRel: out[b][c] = dot(x_b, cls_c) / max(|x_b||cls_c|, 1e-8); 1.0 if cls_c has inf.
// bf16 MFMA tall-skinny GEMM. A-stream now loaded DIRECTLY to registers
// (the previous LDS DMA was a per-lane identity round-trip: lane L wrote and
// read back its own 16B — pure FIFO). Dropping it:
//   - LDS 64KB -> 32KB (Bfrag only) => 3 blocks/CU (12 waves/CU) vs 2 (8 waves)
//   - removes 2x256MB of LDS traffic + manual vmcnt juggling
//   - depth-2 register prefetch (3 windows live = 48 VGPRs for A)
// Memory access pattern is bit-identical to the DMA version (16 rows x 64B
// segments per load instruction), so coalescing is unchanged.

typedef __attribute__((ext_vector_type(8))) short bf16x8;   // 8 bf16 (4 VGPRs)
typedef __attribute__((ext_vector_type(4))) float f32x4;    // MFMA C/D

#define EPS 1e-8f

__device__ __forceinline__ short f2bf(float f) {
  // fp32 -> bf16 round-to-nearest-even (preserves inf)
  union { float f; unsigned u; } v; v.f = f;
  unsigned r = v.u + 0x7fffu + ((v.u >> 16) & 1u);
  return (short)(r >> 16);
}
__device__ __forceinline__ float bf2f(short s) {
  union { float f; unsigned u; } v;
  v.u = ((unsigned)(unsigned short)s) << 16;
  return v.f;
}

// MFMA k-slot map (both A and B): slot j of quad q <-> k = (j>>2)*16 + q*4 + (j&3)

__global__ __launch_bounds__(256, 3) void simrel_kernel(
    const float* __restrict__ X,    // Brows x 256
    const float* __restrict__ CLS,  // 64 x 256
    float* __restrict__ OUT)        // Brows x 64
{
  // B: [ks8][nt4][lane64][8 bf16] = 32 KB (fragment layout, read at lane*16)
  __shared__ __align__(16) short Bfrag[8 * 4 * 64 * 8];

  const int tid  = threadIdx.x;
  const int wave = tid >> 6;
  const int lane = tid & 63;
  const int m    = lane & 15;
  const int quad = lane >> 4;

  // ---- stage B (class_avgs) -> bf16 fragment layout ----
  {
    const int c  = tid >> 2;       // class 0..63
    const int qq = tid & 3;        // 64-float quarter
    const float4* src = (const float4*)CLS + c * 64 + qq * 16;
#pragma unroll
    for (int i = 0; i < 16; ++i) {
      float4 v = src[i];
      const int wabs = qq * 64 + i * 4;
      const int ks = wabs >> 5;
      const int w0 = wabs & 31;
      const int h  = w0 >> 4;
      const int qd = (w0 >> 2) & 3;
      const int lb = (qd << 4) | (c & 15);
      const int nt = c >> 4;
      *(short4*)&Bfrag[((ks * 4 + nt) * 64 + lb) * 8 + h * 4] =
          make_short4(f2bf(v.x), f2bf(v.y), f2bf(v.z), f2bf(v.w));
    }
  }
  __syncthreads();

  const size_t rowbase = (size_t)blockIdx.x * 128 + (size_t)wave * 32;

  // lane's global base per (mti, h); k-step window ks adds ks*32 floats
  const float* gbase[2][2];
#pragma unroll
  for (int mti = 0; mti < 2; ++mti)
#pragma unroll
    for (int h = 0; h < 2; ++h)
      gbase[mti][h] = X + (rowbase + mti * 16 + m) * 256 + h * 16 + quad * 4;

  // prime two windows into registers (in flight while we compute class norms)
  float4 Acur[2][2], Anxt[2][2];
#pragma unroll
  for (int mti = 0; mti < 2; ++mti)
#pragma unroll
    for (int h = 0; h < 2; ++h) {
      Acur[mti][h] = *(const float4*)(gbase[mti][h]);
      Anxt[mti][h] = *(const float4*)(gbase[mti][h] + 32);
    }

  // ---- per-wave class norms + inf flags from staged bf16 (overlaps loads) ----
  float cnv[4]; int cflag[4];
#pragma unroll
  for (int nt = 0; nt < 4; ++nt) {
    float s = 0.f;
#pragma unroll
    for (int ks = 0; ks < 8; ++ks) {
      bf16x8 b = *(const bf16x8*)&Bfrag[((ks * 4 + nt) * 64 + lane) * 8];
#pragma unroll
      for (int j = 0; j < 8; ++j) { float f = bf2f(b[j]); s += f * f; }
    }
    s += __shfl_xor(s, 16);
    s += __shfl_xor(s, 32);
    cflag[nt] = !isfinite(s);   // inf in class -> sentinel 1.0
    cnv[nt]   = sqrtf(s);
  }

  f32x4 acc[2][4];
#pragma unroll
  for (int mti = 0; mti < 2; ++mti)
#pragma unroll
    for (int nt = 0; nt < 4; ++nt)
      acc[mti][nt] = (f32x4){0.f, 0.f, 0.f, 0.f};
  float ssqr[2] = {0.f, 0.f};

#pragma unroll
  for (int ks = 0; ks < 8; ++ks) {
    // issue window ks+2 early (depth-2 prefetch)
    float4 Apre[2][2];
    if (ks < 6) {
#pragma unroll
      for (int mti = 0; mti < 2; ++mti)
#pragma unroll
        for (int h = 0; h < 2; ++h)
          Apre[mti][h] = *(const float4*)(gbase[mti][h] + (ks + 2) * 32);
    }

    bf16x8 bw[4];
#pragma unroll
    for (int nt = 0; nt < 4; ++nt)
      bw[nt] = *(const bf16x8*)&Bfrag[((ks * 4 + nt) * 64 + lane) * 8];

#pragma unroll
    for (int mti = 0; mti < 2; ++mti) {
      float4 a0 = Acur[mti][0];
      float4 a1 = Acur[mti][1];
      ssqr[mti] += a0.x * a0.x + a0.y * a0.y + a0.z * a0.z + a0.w * a0.w +
                   a1.x * a1.x + a1.y * a1.y + a1.z * a1.z + a1.w * a1.w;
      bf16x8 af;
      af[0] = f2bf(a0.x); af[1] = f2bf(a0.y); af[2] = f2bf(a0.z); af[3] = f2bf(a0.w);
      af[4] = f2bf(a1.x); af[5] = f2bf(a1.y); af[6] = f2bf(a1.z); af[7] = f2bf(a1.w);
#pragma unroll
      for (int nt = 0; nt < 4; ++nt)
        acc[mti][nt] =
            __builtin_amdgcn_mfma_f32_16x16x32_bf16(af, bw[nt], acc[mti][nt], 0, 0, 0);
    }

    // rotate the pipeline
#pragma unroll
    for (int mti = 0; mti < 2; ++mti)
#pragma unroll
      for (int h = 0; h < 2; ++h) {
        Acur[mti][h] = Anxt[mti][h];
        if (ks < 6) Anxt[mti][h] = Apre[mti][h];
      }
  }

  // ---- epilogue: norms, divide, store ----
#pragma unroll
  for (int mti = 0; mti < 2; ++mti) {
    float s = ssqr[mti];
    s += __shfl_xor(s, 16);
    s += __shfl_xor(s, 32);
    float xn = sqrtf(s);  // norm of row rowbase + mti*16 + m
    float xnr[4];
#pragma unroll
    for (int r = 0; r < 4; ++r)
      xnr[r] = __shfl(xn, quad * 4 + r);  // norm for C/D row quad*4+r
#pragma unroll
    for (int nt = 0; nt < 4; ++nt) {
      const int n = nt * 16 + m;          // C/D col = lane&15
#pragma unroll
      for (int r = 0; r < 4; ++r) {
        const size_t row = rowbase + mti * 16 + quad * 4 + r;
        const float d = fmaxf(xnr[r] * cnv[nt], EPS);
        const float v =
            cflag[nt] ? 1.0f : acc[mti][nt][r] * __builtin_amdgcn_rcpf(d);
        OUT[row * 64 + n] = v;
      }
    }
  }
}

extern "C" void kernel_launch(void* const* d_in, const int* in_sizes, int n_in,
                              void* d_out, int out_size, void* d_ws, size_t ws_size,
                              hipStream_t stream) {
  (void)n_in; (void)d_ws; (void)ws_size; (void)out_size;
  const float* X   = (const float*)d_in[0];   // inputs, fp32 B x 256
  // d_in[1] = labels (unused by the reference output)
  const float* CLS = (const float*)d_in[2];   // class_avgs, fp32 64 x 256
  float* OUT = (float*)d_out;

  const int Brows  = in_sizes[0] / 256;       // 262144
  const int blocks = Brows / 128;             // 2048 (128 rows per block)
  simrel_kernel<<<blocks, 256, 0, stream>>>(X, CLS, OUT);
}

// Round 2
// 382.053 us; speedup vs baseline: 1.1153x; 1.1153x over previous
//
#include <hip/hip_runtime.h>
#include <math.h>

// SimRel: out[b][c] = dot(x_b, cls_c) / max(|x_b||cls_c|, 1e-8); 1.0 if cls_c has inf.
// bf16 MFMA tall-skinny GEMM, round-0 LDS-DMA structure (wave-private double
// buffers, manual vmcnt, no __syncthreads in main loop) + two changes:
//   1. prep kernel precomputes bf16 Bfrag layout + class norms ONCE into d_ws
//      (round-0 recomputed both in every of the 2048 blocks: ~2-3k VALU cyc/wave).
//      Main kernel stages Bfrag via 8 linear global_load_lds per thread.
//   2. MFMA operands SWAPPED: mfma(B, A) -> D rows = classes, D cols = X-rows.
//      Lane's 4 acc regs = 4 consecutive classes of ONE output row
//      -> epilogue is 8 global_store_dwordx4 per lane instead of 32 dword stores,
//      and x-norm needs no cross-lane gather.

typedef __attribute__((ext_vector_type(8))) short bf16x8;   // 8 bf16 (4 VGPRs)
typedef __attribute__((ext_vector_type(4))) float f32x4;    // MFMA C/D

#define EPS 1e-8f

__device__ __forceinline__ short f2bf(float f) {
  // fp32 -> bf16 round-to-nearest-even (preserves inf)
  union { float f; unsigned u; } v; v.f = f;
  unsigned r = v.u + 0x7fffu + ((v.u >> 16) & 1u);
  return (short)(r >> 16);
}

// async 16B/lane global->LDS DMA; lds base wave-uniform, lane L lands at +L*16;
// global src address is PER-LANE.
__device__ __forceinline__ void dma16(const void* g, void* l) {
  __builtin_amdgcn_global_load_lds(
      (const __attribute__((address_space(1))) void*)g,
      (__attribute__((address_space(3))) void*)l, 16, 0, 0);
}

// ---------------- prep: Bfrag layout + class norms, once ----------------
// 4 blocks x 256 threads; block b owns classes [b*16, b*16+16).
// CN[c] = -1.0 if class c contains inf, else ||cls_c||_2 (fp32).
__global__ __launch_bounds__(256) void simrel_prep(
    const float* __restrict__ CLS, short* __restrict__ Bws,
    float* __restrict__ CNws)
{
  const int t   = threadIdx.x;
  const int c   = blockIdx.x * 16 + (t >> 4);  // class
  const int s16 = t & 15;                      // which 16-float chunk of the row
  const float4* src = (const float4*)(CLS + c * 256 + s16 * 16);
  float s = 0.f, fl = 0.f;
#pragma unroll
  for (int i = 0; i < 4; ++i) {
    float4 v = src[i];
    s += v.x * v.x + v.y * v.y + v.z * v.z + v.w * v.w;
    if (isinf(v.x) || isinf(v.y) || isinf(v.z) || isinf(v.w)) fl = 1.f;
    // MFMA B-fragment layout (k-slot map: slot j of quad q <-> k=(j>>2)*16+q*4+(j&3))
    const int wabs = s16 * 16 + i * 4;
    const int ks = wabs >> 5;
    const int w0 = wabs & 31;
    const int h  = w0 >> 4;
    const int qd = (w0 >> 2) & 3;
    const int lb = (qd << 4) | (c & 15);
    const int nt = c >> 4;
    *(short4*)&Bws[((ks * 4 + nt) * 64 + lb) * 8 + h * 4] =
        make_short4(f2bf(v.x), f2bf(v.y), f2bf(v.z), f2bf(v.w));
  }
  // reduce across the 16 threads sharing a class (consecutive lanes)
  s  += __shfl_xor(s, 1);  s  += __shfl_xor(s, 2);
  s  += __shfl_xor(s, 4);  s  += __shfl_xor(s, 8);
  fl += __shfl_xor(fl, 1); fl += __shfl_xor(fl, 2);
  fl += __shfl_xor(fl, 4); fl += __shfl_xor(fl, 8);
  if (s16 == 0) CNws[c] = (fl > 0.f) ? -1.0f : sqrtf(s);
}

// ---------------- main kernel ----------------
__global__ __launch_bounds__(256) void simrel_kernel(
    const float* __restrict__ X,     // Brows x 256
    const short* __restrict__ Bws,   // precomputed bf16 fragment layout (32KB)
    const float* __restrict__ CNws,  // 64 class norms (sign-encoded inf flag)
    float* __restrict__ OUT)         // Brows x 64
{
  // A: [wave][buf2][mti2][h2][lane64][4 floats] = 32 KB (fp32, DMA-filled)
  __shared__ __align__(16) float Abuf[4 * 2048];
  // B: [ks8][nt4][lane64][8 bf16] = 32 KB
  __shared__ __align__(16) short Bfrag[8 * 4 * 64 * 8];

  const int tid  = threadIdx.x;
  const int wave = tid >> 6;
  const int lane = tid & 63;
  const int m    = lane & 15;
  const int quad = lane >> 4;

  const size_t rowbase = (size_t)blockIdx.x * 128 + (size_t)wave * 32;

  // lane's global gather base per (mti, h); k-step window ks adds ks*32 floats
  const float* gbase[2][2];
#pragma unroll
  for (int mti = 0; mti < 2; ++mti)
#pragma unroll
    for (int h = 0; h < 2; ++h)
      gbase[mti][h] = X + (rowbase + mti * 16 + m) * 256 + h * 16 + quad * 4;

  float* abase = &Abuf[wave * 2048];  // wave-private 8KB (2 buffers x 4KB)

  // prime: window 0 -> buf 0  (4 x 1KB DMA; each inst = 16 rows x 64B lines)
#pragma unroll
  for (int mti = 0; mti < 2; ++mti)
#pragma unroll
    for (int h = 0; h < 2; ++h)
      dma16(gbase[mti][h], abase + (mti * 2 + h) * 256);

  // stage Bfrag: linear 32KB copy, 8 x 1KB DMA per wave
  {
    const char* bs = (const char*)Bws;
    char* bd = (char*)Bfrag;
#pragma unroll
    for (int i = 0; i < 8; ++i) {
      const int off = (wave * 8 + i) * 1024;
      dma16(bs + off + lane * 16, bd + off);
    }
  }

  // class-norm table: lane needs classes nt*16 + quad*4 + r  (one float4 per nt)
  f32x4 cnq[4];
#pragma unroll
  for (int nt = 0; nt < 4; ++nt)
    cnq[nt] = *(const f32x4*)(CNws + nt * 16 + quad * 4);

  __syncthreads();  // drains vmcnt: window0 + Bfrag resident

  f32x4 acc[2][4];
#pragma unroll
  for (int mti = 0; mti < 2; ++mti)
#pragma unroll
    for (int nt = 0; nt < 4; ++nt)
      acc[mti][nt] = (f32x4){0.f, 0.f, 0.f, 0.f};
  float ssqr[2] = {0.f, 0.f};

#pragma unroll
  for (int ks = 0; ks < 8; ++ks) {
    if (ks < 7) {
      // issue window ks+1 into the other buffer, then wait for window ks
      const int nb = (ks + 1) & 1;
#pragma unroll
      for (int mti = 0; mti < 2; ++mti)
#pragma unroll
        for (int h = 0; h < 2; ++h)
          dma16(gbase[mti][h] + (ks + 1) * 32, abase + (nb * 4 + mti * 2 + h) * 256);
      asm volatile("s_waitcnt vmcnt(4)" ::: "memory");
    } else {
      asm volatile("s_waitcnt vmcnt(0)" ::: "memory");
    }
    const int cb = ks & 1;

    bf16x8 bw[4];
#pragma unroll
    for (int nt = 0; nt < 4; ++nt)
      bw[nt] = *(const bf16x8*)&Bfrag[((ks * 4 + nt) * 64 + lane) * 8];

#pragma unroll
    for (int mti = 0; mti < 2; ++mti) {
      float4 a0 = *(const float4*)(abase + (cb * 4 + mti * 2 + 0) * 256 + lane * 4);
      float4 a1 = *(const float4*)(abase + (cb * 4 + mti * 2 + 1) * 256 + lane * 4);
      ssqr[mti] += a0.x * a0.x + a0.y * a0.y + a0.z * a0.z + a0.w * a0.w +
                   a1.x * a1.x + a1.y * a1.y + a1.z * a1.z + a1.w * a1.w;
      bf16x8 af;
      af[0] = f2bf(a0.x); af[1] = f2bf(a0.y); af[2] = f2bf(a0.z); af[3] = f2bf(a0.w);
      af[4] = f2bf(a1.x); af[5] = f2bf(a1.y); af[6] = f2bf(a1.z); af[7] = f2bf(a1.w);
      // SWAPPED operands: D rows = classes, D cols = X-rows.
      // Lane (m,quad), reg r of acc[mti][nt] = OUT[rowbase+mti*16+m][nt*16+quad*4+r]
#pragma unroll
      for (int nt = 0; nt < 4; ++nt)
        acc[mti][nt] =
            __builtin_amdgcn_mfma_f32_16x16x32_bf16(bw[nt], af, acc[mti][nt], 0, 0, 0);
    }
  }

  // ---- epilogue: norms, divide, vectorized store ----
#pragma unroll
  for (int mti = 0; mti < 2; ++mti) {
    float s = ssqr[mti];
    s += __shfl_xor(s, 16);
    s += __shfl_xor(s, 32);
    const float xn = sqrtf(s);  // norm of row rowbase + mti*16 + m (this lane's row)
    const size_t row = rowbase + mti * 16 + m;
#pragma unroll
    for (int nt = 0; nt < 4; ++nt) {
      f32x4 o;
#pragma unroll
      for (int r = 0; r < 4; ++r) {
        const float cn = cnq[nt][r];
        const float d = fmaxf(xn * cn, EPS);
        const float v = acc[mti][nt][r] * __builtin_amdgcn_rcpf(d);
        o[r] = (cn < 0.f) ? 1.0f : v;  // sentinel: class had inf
      }
      *(f32x4*)&OUT[row * 64 + nt * 16 + quad * 4] = o;  // 16B aligned
    }
  }
}

extern "C" void kernel_launch(void* const* d_in, const int* in_sizes, int n_in,
                              void* d_out, int out_size, void* d_ws, size_t ws_size,
                              hipStream_t stream) {
  (void)n_in; (void)ws_size; (void)out_size;
  const float* X   = (const float*)d_in[0];   // inputs, fp32 B x 256
  // d_in[1] = labels (unused by the reference output)
  const float* CLS = (const float*)d_in[2];   // class_avgs, fp32 64 x 256
  float* OUT = (float*)d_out;

  short* Bws  = (short*)d_ws;                       // 32 KB bf16 fragment layout
  float* CNws = (float*)((char*)d_ws + 32768);      // 64 class norms

  const int Brows  = in_sizes[0] / 256;       // 262144
  const int blocks = Brows / 128;             // 2048 (128 rows per block)

  simrel_prep<<<4, 256, 0, stream>>>(CLS, Bws, CNws);
  simrel_kernel<<<blocks, 256, 0, stream>>>(X, Bws, CNws, OUT);
}